// Round 4
// baseline (797.505 us; speedup 1.0000x reference)
//
#include <hip/hip_runtime.h>
#include <hip/hip_bf16.h>

#define M_TOK 16384   // B*S
#define DDIM  1024
#define NEXP  8

typedef __bf16 bf16x8 __attribute__((ext_vector_type(8)));
typedef float  floatx4 __attribute__((ext_vector_type(4)));

__device__ __forceinline__ void gload_lds16(const void* g, void* l) {
    __builtin_amdgcn_global_load_lds(
        (__attribute__((address_space(1))) void*)(void*)g,
        (__attribute__((address_space(3))) void*)l,
        16, 0, 0);
}

// ---------------------------------------------------------------------------
// Kernel 1: route logits + softmax -> rw [M,8] fp32, and h -> bf16
// ---------------------------------------------------------------------------
__global__ __launch_bounds__(256) void route_kernel(
    const float* __restrict__ h, const float* __restrict__ Wr,
    const float* __restrict__ br, __bf16* __restrict__ hbf,
    float* __restrict__ rw)
{
    __shared__ float Wrs[NEXP * DDIM];
    const int tid = threadIdx.x;
    {
        const float4* s4 = (const float4*)Wr;
        float4* d4 = (float4*)Wrs;
        #pragma unroll
        for (int j = 0; j < 8; ++j) d4[j * 256 + tid] = s4[j * 256 + tid];
    }
    __syncthreads();

    const int wave = tid >> 6, lane = tid & 63;
    const int m = blockIdx.x * 4 + wave;

    const float4* hrow = (const float4*)(h + (size_t)m * DDIM + lane * 16);
    float a[16];
    #pragma unroll
    for (int i = 0; i < 4; ++i) {
        float4 v = hrow[i];
        a[i*4+0] = v.x; a[i*4+1] = v.y; a[i*4+2] = v.z; a[i*4+3] = v.w;
    }
    bf16x8 o0, o1;
    #pragma unroll
    for (int i = 0; i < 8; ++i) { o0[i] = (__bf16)a[i]; o1[i] = (__bf16)a[8 + i]; }
    *(bf16x8*)(hbf + (size_t)m * DDIM + lane * 16)     = o0;
    *(bf16x8*)(hbf + (size_t)m * DDIM + lane * 16 + 8) = o1;

    float p[NEXP];
    #pragma unroll
    for (int e = 0; e < NEXP; ++e) {
        const float4* w4 = (const float4*)&Wrs[e * DDIM + lane * 16];
        float s = 0.f;
        #pragma unroll
        for (int i = 0; i < 4; ++i) {
            float4 wv = w4[i];
            s += a[i*4+0]*wv.x + a[i*4+1]*wv.y + a[i*4+2]*wv.z + a[i*4+3]*wv.w;
        }
        p[e] = s;
    }
    #pragma unroll
    for (int e = 0; e < NEXP; ++e) {
        #pragma unroll
        for (int off = 32; off > 0; off >>= 1)
            p[e] += __shfl_xor(p[e], off, 64);
    }
    if (lane == 0) {
        float l[NEXP], mx = -1e30f;
        #pragma unroll
        for (int e = 0; e < NEXP; ++e) { l[e] = p[e] + br[e]; mx = fmaxf(mx, l[e]); }
        float s = 0.f;
        #pragma unroll
        for (int e = 0; e < NEXP; ++e) { l[e] = expf(l[e] - mx); s += l[e]; }
        float inv = 1.f / s;
        float4 r0 = {l[0]*inv, l[1]*inv, l[2]*inv, l[3]*inv};
        float4 r1 = {l[4]*inv, l[5]*inv, l[6]*inv, l[7]*inv};
        *(float4*)(rw + (size_t)m * NEXP)     = r0;
        *(float4*)(rw + (size_t)m * NEXP + 4) = r1;
    }
}

// ---------------------------------------------------------------------------
// Kernel 2: W_edges fp32 -> bf16 (contiguous), 16 elems/thread
// ---------------------------------------------------------------------------
__global__ __launch_bounds__(256) void convw_kernel(
    const float* __restrict__ src, __bf16* __restrict__ dst)
{
    size_t base = ((size_t)blockIdx.x * 256 + threadIdx.x) * 16;
    const float4* s4 = (const float4*)(src + base);
    float a[16];
    #pragma unroll
    for (int i = 0; i < 4; ++i) {
        float4 v = s4[i];
        a[i*4+0] = v.x; a[i*4+1] = v.y; a[i*4+2] = v.z; a[i*4+3] = v.w;
    }
    bf16x8 o0, o1;
    #pragma unroll
    for (int i = 0; i < 8; ++i) { o0[i] = (__bf16)a[i]; o1[i] = (__bf16)a[8 + i]; }
    *(bf16x8*)(dst + base)     = o0;
    *(bf16x8*)(dst + base + 8) = o1;
}

// ---------------------------------------------------------------------------
// Kernel 3 (x8 dispatches): plain bf16 GEMM for ONE expert, m97 structure.
// 128x128 tile, BK=64, single facc (64 acc regs -> no spill), XOR-swizzled LDS.
// Epilogue: partial-accumulate  out += rw[m,e] * (h @ W_e^T)  in fp32.
//   mode 0 (e==0):  out  = w*facc            (d_out is poison -> plain store)
//   mode 1 (mid):   out += w*facc
//   mode 2 (e==7):  x = out + w*facc + bias; out = GELU_exact(x)
// Inter-dispatch visibility via stream ordering (same guarantee hbf relies on).
// ---------------------------------------------------------------------------
__global__ __launch_bounds__(256, 2) void gemm_expert_kernel(
    const __bf16* __restrict__ hbf, const __bf16* __restrict__ Wbf,
    const float* __restrict__ rw, const float* __restrict__ bias,
    float* __restrict__ outp, int e, int mode)
{
    __shared__ __bf16 As[128 * 64];
    __shared__ __bf16 Bs[128 * 64];

    const int tid  = threadIdx.x;
    const int wave = tid >> 6, lane = tid & 63;
    const int quad = lane >> 4, l16 = lane & 15;
    const int wm = wave & 1, wn = wave >> 1;
    const int m0 = blockIdx.y * 128, f0 = blockIdx.x * 128;

    const floatx4 z4 = {0.f, 0.f, 0.f, 0.f};
    floatx4 facc[4][4];
    #pragma unroll
    for (int i = 0; i < 4; ++i) {
        #pragma unroll
        for (int j = 0; j < 4; ++j) facc[i][j] = z4;
    }

    // XOR-swizzled LDS slots (conflict-free, verified r2: conflicts 1.02e8 -> 1e6)
    int aslot[2][4], bslot[2][4];
    #pragma unroll
    for (int s = 0; s < 2; ++s) {
        #pragma unroll
        for (int f = 0; f < 4; ++f) {
            int ra = wm*64 + f*16 + l16;
            int rb = wn*64 + f*16 + l16;
            int grp = s*4 + quad;
            aslot[s][f] = ra*8 + ((grp ^ ra) & 7);
            bslot[s][f] = rb*8 + ((grp ^ rb) & 7);
        }
    }

    for (int k0 = 0; k0 < DDIM; k0 += 64) {
        __syncthreads();
        #pragma unroll
        for (int t = 0; t < 4; ++t) {
            int g   = t * 256 + tid;
            int row = g >> 3;
            int c   = ((g ^ row) & 7) * 8;   // swizzled column group
            gload_lds16(hbf + (size_t)(m0 + row) * DDIM + k0 + c, (char*)As + g * 16);
            gload_lds16(Wbf + (size_t)(f0 + row) * DDIM + k0 + c, (char*)Bs + g * 16);
        }
        __syncthreads();

        #pragma unroll
        for (int s = 0; s < 2; ++s) {
            bf16x8 av[4], bv[4];
            #pragma unroll
            for (int mf = 0; mf < 4; ++mf)
                av[mf] = *(const bf16x8*)&As[aslot[s][mf] * 8];
            #pragma unroll
            for (int nf = 0; nf < 4; ++nf)
                bv[nf] = *(const bf16x8*)&Bs[bslot[s][nf] * 8];
            #pragma unroll
            for (int mf = 0; mf < 4; ++mf) {
                #pragma unroll
                for (int nf = 0; nf < 4; ++nf)
                    facc[mf][nf] = __builtin_amdgcn_mfma_f32_16x16x32_bf16(
                        av[mf], bv[nf], facc[mf][nf], 0, 0, 0);
            }
        }
    }

    // per-row routing weight (quad-uniform -> one cache line per quad)
    float wrow[4][4];
    #pragma unroll
    for (int mf = 0; mf < 4; ++mf) {
        #pragma unroll
        for (int r = 0; r < 4; ++r)
            wrow[mf][r] = rw[(size_t)(m0 + wm*64 + mf*16 + quad*4 + r) * NEXP + e];
    }

    #pragma unroll
    for (int nf = 0; nf < 4; ++nf) {
        int gf = f0 + wn*64 + nf*16 + l16;
        float bval = (mode == 2) ? bias[gf] : 0.f;
        #pragma unroll
        for (int mf = 0; mf < 4; ++mf) {
            int gm = m0 + wm*64 + mf*16 + quad*4;
            #pragma unroll
            for (int r = 0; r < 4; ++r) {
                size_t idx = (size_t)(gm + r) * DDIM + gf;
                float v = wrow[mf][r] * facc[mf][nf][r];
                if (mode == 0) {
                    outp[idx] = v;
                } else if (mode == 1) {
                    outp[idx] += v;
                } else {
                    float x = outp[idx] + v + bval;
                    outp[idx] = 0.5f * x * (1.0f + erff(x * 0.70710678118f));
                }
            }
        }
    }
}

// ---------------------------------------------------------------------------
extern "C" void kernel_launch(void* const* d_in, const int* in_sizes, int n_in,
                              void* d_out, int out_size, void* d_ws, size_t ws_size,
                              hipStream_t stream) {
    const float* h    = (const float*)d_in[0];   // [4,4096,1024]
    const float* Wr   = (const float*)d_in[1];   // [8,1024]
    const float* br   = (const float*)d_in[2];   // [8]
    const float* We   = (const float*)d_in[3];   // [8,1024,1024]
    const float* bias = (const float*)d_in[4];   // [1024]
    float* outp = (float*)d_out;
    char* ws = (char*)d_ws;

    __bf16* hbf  = (__bf16*)ws;                                   // 32 MiB
    __bf16* Webf = (__bf16*)(ws + (size_t)M_TOK * DDIM * 2);      // 16 MiB
    float*  rwp  = (float*)(ws + (size_t)M_TOK * DDIM * 2
                               + (size_t)NEXP * DDIM * DDIM * 2); // 512 KiB

    hipLaunchKernelGGL(route_kernel, dim3(M_TOK / 4), dim3(256), 0, stream,
                       h, Wr, br, hbf, rwp);
    hipLaunchKernelGGL(convw_kernel, dim3((NEXP * DDIM * DDIM) / (256 * 16)),
                       dim3(256), 0, stream, We, Webf);

    for (int e = 0; e < NEXP; ++e) {
        int mode = (e == 0) ? 0 : (e == NEXP - 1 ? 2 : 1);
        hipLaunchKernelGGL(gemm_expert_kernel, dim3(DDIM / 128, M_TOK / 128),
                           dim3(256), 0, stream,
                           hbf, Webf + (size_t)e * DDIM * DDIM, rwp, bias,
                           outp, e, mode);
    }
}

// Round 5
// 506.936 us; speedup vs baseline: 1.5732x; 1.5732x over previous
//
#include <hip/hip_runtime.h>
#include <hip/hip_bf16.h>

#define M_TOK 16384   // B*S
#define DDIM  1024
#define NEXP  8
#define KP    (NEXP * DDIM)   // 8192 fused K

typedef __bf16 bf16x8 __attribute__((ext_vector_type(8)));
typedef float  floatx4 __attribute__((ext_vector_type(4)));

__device__ __forceinline__ void gload_lds16(const void* g, void* l) {
    __builtin_amdgcn_global_load_lds(
        (__attribute__((address_space(1))) void*)(void*)g,
        (__attribute__((address_space(3))) void*)l,
        16, 0, 0);
}

// ---------------------------------------------------------------------------
// Kernel 1: route logits + softmax -> rw [M,8] fp32, and h -> bf16
// ---------------------------------------------------------------------------
__global__ __launch_bounds__(256) void route_kernel(
    const float* __restrict__ h, const float* __restrict__ Wr,
    const float* __restrict__ br, __bf16* __restrict__ hbf,
    float* __restrict__ rw)
{
    __shared__ float Wrs[NEXP * DDIM];
    const int tid = threadIdx.x;
    {
        const float4* s4 = (const float4*)Wr;
        float4* d4 = (float4*)Wrs;
        #pragma unroll
        for (int j = 0; j < 8; ++j) d4[j * 256 + tid] = s4[j * 256 + tid];
    }
    __syncthreads();

    const int wave = tid >> 6, lane = tid & 63;
    const int m = blockIdx.x * 4 + wave;

    const float4* hrow = (const float4*)(h + (size_t)m * DDIM + lane * 16);
    float a[16];
    #pragma unroll
    for (int i = 0; i < 4; ++i) {
        float4 v = hrow[i];
        a[i*4+0] = v.x; a[i*4+1] = v.y; a[i*4+2] = v.z; a[i*4+3] = v.w;
    }
    bf16x8 o0, o1;
    #pragma unroll
    for (int i = 0; i < 8; ++i) { o0[i] = (__bf16)a[i]; o1[i] = (__bf16)a[8 + i]; }
    *(bf16x8*)(hbf + (size_t)m * DDIM + lane * 16)     = o0;
    *(bf16x8*)(hbf + (size_t)m * DDIM + lane * 16 + 8) = o1;

    float p[NEXP];
    #pragma unroll
    for (int e = 0; e < NEXP; ++e) {
        const float4* w4 = (const float4*)&Wrs[e * DDIM + lane * 16];
        float s = 0.f;
        #pragma unroll
        for (int i = 0; i < 4; ++i) {
            float4 wv = w4[i];
            s += a[i*4+0]*wv.x + a[i*4+1]*wv.y + a[i*4+2]*wv.z + a[i*4+3]*wv.w;
        }
        p[e] = s;
    }
    #pragma unroll
    for (int e = 0; e < NEXP; ++e) {
        #pragma unroll
        for (int off = 32; off > 0; off >>= 1)
            p[e] += __shfl_xor(p[e], off, 64);
    }
    if (lane == 0) {
        float l[NEXP], mx = -1e30f;
        #pragma unroll
        for (int e = 0; e < NEXP; ++e) { l[e] = p[e] + br[e]; mx = fmaxf(mx, l[e]); }
        float s = 0.f;
        #pragma unroll
        for (int e = 0; e < NEXP; ++e) { l[e] = expf(l[e] - mx); s += l[e]; }
        float inv = 1.f / s;
        float4 r0 = {l[0]*inv, l[1]*inv, l[2]*inv, l[3]*inv};
        float4 r1 = {l[4]*inv, l[5]*inv, l[6]*inv, l[7]*inv};
        *(float4*)(rw + (size_t)m * NEXP)     = r0;
        *(float4*)(rw + (size_t)m * NEXP + 4) = r1;
    }
}

// ---------------------------------------------------------------------------
// Kernel 2: W_edges [e][f][k] fp32 -> B'[f][e*1024+k] bf16
// ---------------------------------------------------------------------------
__global__ __launch_bounds__(256) void convw2_kernel(
    const float* __restrict__ src, __bf16* __restrict__ dst)
{
    size_t idx = ((size_t)blockIdx.x * 256 + threadIdx.x) * 16;
    int e = (int)(idx >> 20);
    int f = (int)(idx >> 10) & 1023;
    int k = (int)idx & 1023;
    const float4* s4 = (const float4*)(src + idx);
    float a[16];
    #pragma unroll
    for (int i = 0; i < 4; ++i) {
        float4 v = s4[i];
        a[i*4+0] = v.x; a[i*4+1] = v.y; a[i*4+2] = v.z; a[i*4+3] = v.w;
    }
    bf16x8 o0, o1;
    #pragma unroll
    for (int i = 0; i < 8; ++i) { o0[i] = (__bf16)a[i]; o1[i] = (__bf16)a[8 + i]; }
    __bf16* d = dst + (size_t)f * KP + (size_t)e * DDIM + k;
    *(bf16x8*)d       = o0;
    *(bf16x8*)(d + 8) = o1;
}

// ---------------------------------------------------------------------------
// Kernel 3: single-dispatch fused MoE GEMM with online expert rescaling.
// m97 structure: 128x128 tile, BK=64, XOR-swizzled LDS, SINGLE 64-reg facc.
// Invariant: entering expert e, facc = (sum_{i<e} w_i*C_i) / w_e  -> MFMA
// accumulates C_e raw; boundary multiplies by w_{e-1}/w_e; final x w_7.
// A (h) repeats every 1024 of K -> per-block A-tile stays L2-hot.
// ---------------------------------------------------------------------------
__global__ __launch_bounds__(256, 3) void gemm_fused_kernel(
    const __bf16* __restrict__ hbf, const __bf16* __restrict__ Bp,
    const float* __restrict__ rw, const float* __restrict__ bias,
    float* __restrict__ outp)
{
    __shared__ __bf16 As[128 * 64];
    __shared__ __bf16 Bs[128 * 64];
    __shared__ float  rws[128 * NEXP];

    const int tid  = threadIdx.x;
    const int wave = tid >> 6, lane = tid & 63;
    const int quad = lane >> 4, l16 = lane & 15;
    const int wm = wave & 1, wn = wave >> 1;
    const int m0 = blockIdx.y * 128, f0 = blockIdx.x * 128;

    // stage routing weights for the block's 128 rows (1024 floats)
    {
        const float4* src = (const float4*)(rw + (size_t)m0 * NEXP);
        ((float4*)rws)[tid] = src[tid];
    }

    const floatx4 z4 = {0.f, 0.f, 0.f, 0.f};
    floatx4 facc[4][4];
    #pragma unroll
    for (int i = 0; i < 4; ++i) {
        #pragma unroll
        for (int j = 0; j < 4; ++j) facc[i][j] = z4;
    }

    // XOR-swizzled LDS read slots (conflict-free, verified r2)
    int aslot[2][4], bslot[2][4];
    #pragma unroll
    for (int s = 0; s < 2; ++s) {
        #pragma unroll
        for (int f = 0; f < 4; ++f) {
            int ra = wm*64 + f*16 + l16;
            int rb = wn*64 + f*16 + l16;
            int grp = s*4 + quad;
            aslot[s][f] = ra*8 + ((grp ^ ra) & 7);
            bslot[s][f] = rb*8 + ((grp ^ rb) & 7);
        }
    }

    __syncthreads();  // rws visible

    float wcur[4][4];   // current expert's routing weight for this lane's 16 rows

    for (int e = 0; e < NEXP; ++e) {
        // boundary: rescale facc by w_{e-1}/w_e  (clamped; ratio bounded by
        // softmax spread, fp32 range is ample)
        #pragma unroll
        for (int mf = 0; mf < 4; ++mf) {
            #pragma unroll
            for (int r = 0; r < 4; ++r) {
                float wn_ = fmaxf(rws[(wm*64 + mf*16 + quad*4 + r) * NEXP + e], 1e-20f);
                if (e > 0) {
                    float ratio = wcur[mf][r] / wn_;
                    #pragma unroll
                    for (int nf = 0; nf < 4; ++nf)
                        facc[mf][nf][r] *= ratio;
                }
                wcur[mf][r] = wn_;
            }
        }

        for (int k0 = 0; k0 < DDIM; k0 += 64) {
            __syncthreads();
            #pragma unroll
            for (int t = 0; t < 4; ++t) {
                int g   = t * 256 + tid;
                int row = g >> 3;
                int c   = ((g ^ row) & 7) * 8;   // swizzled column group
                gload_lds16(hbf + (size_t)(m0 + row) * DDIM + k0 + c,
                            (char*)As + g * 16);
                gload_lds16(Bp + (size_t)(f0 + row) * KP + e * DDIM + k0 + c,
                            (char*)Bs + g * 16);
            }
            __syncthreads();

            #pragma unroll
            for (int s = 0; s < 2; ++s) {
                bf16x8 av[4], bv[4];
                #pragma unroll
                for (int mf = 0; mf < 4; ++mf)
                    av[mf] = *(const bf16x8*)&As[aslot[s][mf] * 8];
                #pragma unroll
                for (int nf = 0; nf < 4; ++nf)
                    bv[nf] = *(const bf16x8*)&Bs[bslot[s][nf] * 8];
                #pragma unroll
                for (int mf = 0; mf < 4; ++mf) {
                    #pragma unroll
                    for (int nf = 0; nf < 4; ++nf)
                        facc[mf][nf] = __builtin_amdgcn_mfma_f32_16x16x32_bf16(
                            av[mf], bv[nf], facc[mf][nf], 0, 0, 0);
                }
            }
        }
    }

    // epilogue: out = GELU(facc * w_7 + bias)
    #pragma unroll
    for (int nf = 0; nf < 4; ++nf) {
        int gf = f0 + wn*64 + nf*16 + l16;
        float bval = bias[gf];
        #pragma unroll
        for (int mf = 0; mf < 4; ++mf) {
            int gm = m0 + wm*64 + mf*16 + quad*4;
            #pragma unroll
            for (int r = 0; r < 4; ++r) {
                float x = facc[mf][nf][r] * wcur[mf][r] + bval;
                float gel = 0.5f * x * (1.0f + erff(x * 0.70710678118f));
                outp[(size_t)(gm + r) * DDIM + gf] = gel;
            }
        }
    }
}

// ---------------------------------------------------------------------------
extern "C" void kernel_launch(void* const* d_in, const int* in_sizes, int n_in,
                              void* d_out, int out_size, void* d_ws, size_t ws_size,
                              hipStream_t stream) {
    const float* h    = (const float*)d_in[0];   // [4,4096,1024]
    const float* Wr   = (const float*)d_in[1];   // [8,1024]
    const float* br   = (const float*)d_in[2];   // [8]
    const float* We   = (const float*)d_in[3];   // [8,1024,1024]
    const float* bias = (const float*)d_in[4];   // [1024]
    float* outp = (float*)d_out;
    char* ws = (char*)d_ws;

    __bf16* hbf = (__bf16*)ws;                                   // 32 MiB
    __bf16* Bp  = (__bf16*)(ws + (size_t)M_TOK * DDIM * 2);      // 16 MiB
    float*  rwp = (float*)(ws + (size_t)M_TOK * DDIM * 2
                              + (size_t)NEXP * DDIM * DDIM * 2); // 512 KiB

    hipLaunchKernelGGL(route_kernel, dim3(M_TOK / 4), dim3(256), 0, stream,
                       h, Wr, br, hbf, rwp);
    hipLaunchKernelGGL(convw2_kernel, dim3((NEXP * DDIM * DDIM) / (256 * 16)),
                       dim3(256), 0, stream, We, Bp);
    hipLaunchKernelGGL(gemm_fused_kernel, dim3(DDIM / 128, M_TOK / 128),
                       dim3(256), 0, stream, hbf, Bp, rwp, bias, outp);
}